// Round 1
// baseline (1195.809 us; speedup 1.0000x reference)
//
#include <hip/hip_runtime.h>

#define NN 50000
#define D 128
#define EE 600000
#define R 8
#define KTOT (R * D + D) /* 1152 */

// ---- count incoming edges per (dst, rel) ----
__global__ __launch_bounds__(256) void cnt_kernel(const int* __restrict__ dst,
                                                  const int* __restrict__ et,
                                                  float* __restrict__ cnt, int E) {
    int e = blockIdx.x * 256 + threadIdx.x;
    if (e < E) atomicAdd(&cnt[(size_t)dst[e] * R + et[e]], 1.0f);
}

__global__ __launch_bounds__(256) void inv_kernel(float* __restrict__ cnt, int n) {
    int i = blockIdx.x * 256 + threadIdx.x;
    if (i < n) cnt[i] = 1.0f / fmaxf(cnt[i], 1.0f);
}

// ---- scatter-sum source features into agg[N,R,D]; one wave per edge ----
__global__ __launch_bounds__(256) void scatter_kernel(const float* __restrict__ x,
                                                      const int* __restrict__ src,
                                                      const int* __restrict__ dst,
                                                      const int* __restrict__ et,
                                                      float* __restrict__ agg, int E) {
    int w = (blockIdx.x * 256 + threadIdx.x) >> 6;
    int lane = threadIdx.x & 63;
    if (w >= E) return;
    const float* xs = x + (size_t)src[w] * D;
    float* ap = agg + ((size_t)dst[w] * R + et[w]) * D;
    atomicAdd(ap + lane, xs[lane]);
    atomicAdd(ap + lane + 64, xs[lane + 64]);
}

// ---- fused GEMM: out[n,:] = relu( [mean(n,0..7,:), x(n,:)] @ [w;root] + b ) ----
// A is virtual [N, 1152]; inv-count scaling applied during A-tile load.
__global__ __launch_bounds__(256) void gemm_kernel(const float* __restrict__ xin,
                                                   const float* __restrict__ agg,
                                                   const float* __restrict__ inv,
                                                   const float* __restrict__ w,
                                                   const float* __restrict__ root,
                                                   const float* __restrict__ bias,
                                                   float* __restrict__ out) {
    __shared__ float At[64][33];   // +1 pad: breaks row-broadcast bank conflicts
    __shared__ float Bt[32][128];

    const int t = threadIdx.x;
    const int n0 = blockIdx.x * 64;
    const int colg = t & 31;   // col base: colg + 32*j
    const int rowg = t >> 5;   // row base: rowg*8 + i

    float acc[8][4];
#pragma unroll
    for (int i = 0; i < 8; ++i)
#pragma unroll
        for (int j = 0; j < 4; ++j) acc[i][j] = 0.f;

    const int arow = t >> 2;       // 0..63 (A-tile row this thread loads)
    const int akk = (t & 3) * 8;   // 8 consecutive k within the 32-chunk

    for (int kc = 0; kc < KTOT / 32; ++kc) {
        const int k0 = kc * 32;

        // B tile: rows k0..k0+31 of stacked [w (1024x128); root (128x128)]
        const float* Brow = (k0 < R * D) ? (w + (size_t)k0 * D)
                                         : (root + (size_t)(k0 - R * D) * D);
        const float4* B4 = (const float4*)Brow;
        float4* Bt4 = (float4*)&Bt[0][0];
#pragma unroll
        for (int i = 0; i < 4; ++i) Bt4[t + 256 * i] = B4[t + 256 * i];

        // A tile
        {
            const int n = n0 + arow;
            float vals[8];
            if (n < NN) {
                if (k0 < R * D) {
                    const int r = k0 >> 7;
                    const float s = inv[(size_t)n * R + r];
                    const float4* a4 =
                        (const float4*)(agg + (size_t)n * (R * D) + k0 + akk);
                    float4 v0 = a4[0], v1 = a4[1];
                    vals[0] = v0.x * s; vals[1] = v0.y * s;
                    vals[2] = v0.z * s; vals[3] = v0.w * s;
                    vals[4] = v1.x * s; vals[5] = v1.y * s;
                    vals[6] = v1.z * s; vals[7] = v1.w * s;
                } else {
                    const float4* a4 =
                        (const float4*)(xin + (size_t)n * D + (k0 - R * D) + akk);
                    float4 v0 = a4[0], v1 = a4[1];
                    vals[0] = v0.x; vals[1] = v0.y; vals[2] = v0.z; vals[3] = v0.w;
                    vals[4] = v1.x; vals[5] = v1.y; vals[6] = v1.z; vals[7] = v1.w;
                }
            } else {
#pragma unroll
                for (int q = 0; q < 8; ++q) vals[q] = 0.f;
            }
#pragma unroll
            for (int q = 0; q < 8; ++q) At[arow][akk + q] = vals[q];
        }
        __syncthreads();

#pragma unroll 4
        for (int kk = 0; kk < 32; ++kk) {
            float bj[4];
#pragma unroll
            for (int j = 0; j < 4; ++j) bj[j] = Bt[kk][colg + 32 * j];
#pragma unroll
            for (int i = 0; i < 8; ++i) {
                float a = At[rowg * 8 + i][kk];
#pragma unroll
                for (int j = 0; j < 4; ++j) acc[i][j] += a * bj[j];
            }
        }
        __syncthreads();
    }

    // epilogue: bias + relu
#pragma unroll
    for (int i = 0; i < 8; ++i) {
        const int n = n0 + rowg * 8 + i;
        if (n < NN) {
#pragma unroll
            for (int j = 0; j < 4; ++j) {
                const int c = colg + 32 * j;
                float v = acc[i][j] + bias[c];
                out[(size_t)n * D + c] = fmaxf(v, 0.f);
            }
        }
    }
}

extern "C" void kernel_launch(void* const* d_in, const int* in_sizes, int n_in,
                              void* d_out, int out_size, void* d_ws, size_t ws_size,
                              hipStream_t stream) {
    const float* x = (const float*)d_in[0];
    const int* ei = (const int*)d_in[1];
    const int* et = (const int*)d_in[2];
    const float* w1 = (const float*)d_in[3];
    const float* root1 = (const float*)d_in[4];
    const float* b1 = (const float*)d_in[5];
    const float* w2 = (const float*)d_in[6];
    const float* root2 = (const float*)d_in[7];
    const float* b2 = (const float*)d_in[8];
    float* out = (float*)d_out;

    char* ws = (char*)d_ws;
    float* cnt = (float*)ws;                                   // N*R fp32 (1.6 MB)
    float* agg = (float*)(ws + 1600000);                       // N*R*D fp32 (204.8 MB)
    float* h = (float*)(ws + 1600000 + (size_t)204800000);     // N*D fp32 (25.6 MB)

    const int* srcp = ei;
    const int* dstp = ei + EE;

    const size_t agg_bytes = (size_t)NN * R * D * sizeof(float);

    // counts + inverse (shared by both layers)
    hipMemsetAsync(cnt, 0, (size_t)NN * R * sizeof(float), stream);
    cnt_kernel<<<(EE + 255) / 256, 256, 0, stream>>>(dstp, et, cnt, EE);
    inv_kernel<<<(NN * R + 255) / 256, 256, 0, stream>>>(cnt, NN * R);

    const int scatter_blocks = EE / 4;  // one wave per edge, 4 waves/block
    const int gemm_blocks = (NN + 63) / 64;

    // layer 1: x -> h
    hipMemsetAsync(agg, 0, agg_bytes, stream);
    scatter_kernel<<<scatter_blocks, 256, 0, stream>>>(x, srcp, dstp, et, agg, EE);
    gemm_kernel<<<gemm_blocks, 256, 0, stream>>>(x, agg, cnt, w1, root1, b1, h);

    // layer 2: h -> out
    hipMemsetAsync(agg, 0, agg_bytes, stream);
    scatter_kernel<<<scatter_blocks, 256, 0, stream>>>(h, srcp, dstp, et, agg, EE);
    gemm_kernel<<<gemm_blocks, 256, 0, stream>>>(h, agg, cnt, w2, root2, b2, out);
}

// Round 2
// 844.862 us; speedup vs baseline: 1.4154x; 1.4154x over previous
//
#include <hip/hip_runtime.h>

#define NN 50000
#define D 128
#define EE 600000
#define R 8
#define NCHUNK 36  /* 1152 / 32 k-chunks */

typedef unsigned short u16;
typedef __attribute__((ext_vector_type(8))) short bf16x8;
typedef __attribute__((ext_vector_type(4))) float f32x4;

__device__ inline u16 f2bf(float f) {
    union { float f; unsigned u; } v; v.f = f;
    unsigned r = (v.u + 0x7FFFu + ((v.u >> 16) & 1u)) >> 16;
    return (u16)r;
}

// ---- count incoming edges per (dst, rel) ----
__global__ __launch_bounds__(256) void cnt_kernel(const int* __restrict__ dst,
                                                  const int* __restrict__ et,
                                                  float* __restrict__ cnt, int E) {
    int e = blockIdx.x * 256 + threadIdx.x;
    if (e < E) atomicAdd(&cnt[(size_t)dst[e] * R + et[e]], 1.0f);
}

__global__ __launch_bounds__(256) void inv_kernel(float* __restrict__ cnt, int n) {
    int i = blockIdx.x * 256 + threadIdx.x;
    if (i < n) cnt[i] = 1.0f / fmaxf(cnt[i], 1.0f);
}

// ---- scatter-sum source features into agg[N,R,D]; one wave per edge ----
__global__ __launch_bounds__(256) void scatter_kernel(const float* __restrict__ x,
                                                      const int* __restrict__ src,
                                                      const int* __restrict__ dst,
                                                      const int* __restrict__ et,
                                                      float* __restrict__ agg, int E) {
    int w = (blockIdx.x * 256 + threadIdx.x) >> 6;
    int lane = threadIdx.x & 63;
    if (w >= E) return;
    const float* xs = x + (size_t)src[w] * D;
    float* ap = agg + ((size_t)dst[w] * R + et[w]) * D;
    atomicAdd(ap + lane, xs[lane]);
    atomicAdd(ap + lane + 64, xs[lane + 64]);
}

// ---- pack B = [w (1024x128); root (128x128)] into bf16 MFMA B-fragment order ----
// Bfrag[kc][g][lane][j] : value B[k = kc*32 + (lane>>4)*8 + j][col = g*16 + (lane&15)]
__global__ __launch_bounds__(256) void bprep_kernel(const float* __restrict__ w,
                                                    const float* __restrict__ root,
                                                    u16* __restrict__ Bfrag) {
    int idx = blockIdx.x * 256 + threadIdx.x;  // over 36*8*64 = 18432
    if (idx >= NCHUNK * 8 * 64) return;
    int lane = idx & 63;
    int g = (idx >> 6) & 7;
    int kc = idx >> 9;
    int col = g * 16 + (lane & 15);
    int kbase = kc * 32 + (lane >> 4) * 8;
    u16* o = Bfrag + (size_t)idx * 8;
#pragma unroll
    for (int j = 0; j < 8; ++j) {
        int k = kbase + j;
        float v = (k < R * D) ? w[(size_t)k * D + col]
                              : root[(size_t)(k - R * D) * D + col];
        o[j] = f2bf(v);
    }
}

// ---- MFMA GEMM: out[n,:] = relu( [mean(n,0..7,:), x(n,:)] @ [w;root] + b ) ----
// 64 rows x 128 cols per block; wave handles 16 rows x 128 cols (8 col-groups).
__global__ __launch_bounds__(256) void gemm_mfma(const float* __restrict__ xin,
                                                 const float* __restrict__ agg,
                                                 const float* __restrict__ inv,
                                                 const u16* __restrict__ Bfrag,
                                                 const float* __restrict__ bias,
                                                 float* __restrict__ out) {
    const int t = threadIdx.x;
    const int wave = t >> 6;
    const int lane = t & 63;
    const int quad = lane >> 4;
    const int l15 = lane & 15;
    const int n0 = blockIdx.x * 64;
    const int n = n0 + wave * 16 + l15;
    const int nc = (n < NN) ? n : (NN - 1);  // clamp for loads; store guarded

    // per-row inverse counts (8 relations)
    float invv[8];
    {
        const float4* ivp = (const float4*)(inv + (size_t)nc * R);
        float4 iv0 = ivp[0], iv1 = ivp[1];
        invv[0] = iv0.x; invv[1] = iv0.y; invv[2] = iv0.z; invv[3] = iv0.w;
        invv[4] = iv1.x; invv[5] = iv1.y; invv[6] = iv1.z; invv[7] = iv1.w;
    }

    f32x4 acc[8];
#pragma unroll
    for (int g = 0; g < 8; ++g) acc[g] = (f32x4){0.f, 0.f, 0.f, 0.f};

    const float* arow = agg + (size_t)nc * (R * D) + quad * 8;
    const u16* bbase = Bfrag + (size_t)lane * 8;

    // relation part: k = 0..1023, scaled by inv count
#pragma unroll
    for (int r = 0; r < R; ++r) {
        const float s = invv[r];
#pragma unroll
        for (int c = 0; c < 4; ++c) {
            const int kc = r * 4 + c;
            const float4* a4 = (const float4*)(arow + kc * 32);
            float4 v0 = a4[0], v1 = a4[1];
            bf16x8 af;
            af[0] = (short)f2bf(v0.x * s); af[1] = (short)f2bf(v0.y * s);
            af[2] = (short)f2bf(v0.z * s); af[3] = (short)f2bf(v0.w * s);
            af[4] = (short)f2bf(v1.x * s); af[5] = (short)f2bf(v1.y * s);
            af[6] = (short)f2bf(v1.z * s); af[7] = (short)f2bf(v1.w * s);
#pragma unroll
            for (int g = 0; g < 8; ++g) {
                bf16x8 bf = *(const bf16x8*)(bbase + ((size_t)(kc * 8 + g)) * 64 * 8);
                acc[g] = __builtin_amdgcn_mfma_f32_16x16x32_bf16(af, bf, acc[g], 0, 0, 0);
            }
        }
    }

    // root part: k = 1024..1151, unscaled, from xin
    {
        const float* xrow = xin + (size_t)nc * D + quad * 8;
#pragma unroll
        for (int c = 0; c < 4; ++c) {
            const int kc = 32 + c;
            const float4* a4 = (const float4*)(xrow + c * 32);
            float4 v0 = a4[0], v1 = a4[1];
            bf16x8 af;
            af[0] = (short)f2bf(v0.x); af[1] = (short)f2bf(v0.y);
            af[2] = (short)f2bf(v0.z); af[3] = (short)f2bf(v0.w);
            af[4] = (short)f2bf(v1.x); af[5] = (short)f2bf(v1.y);
            af[6] = (short)f2bf(v1.z); af[7] = (short)f2bf(v1.w);
#pragma unroll
            for (int g = 0; g < 8; ++g) {
                bf16x8 bf = *(const bf16x8*)(bbase + ((size_t)(kc * 8 + g)) * 64 * 8);
                acc[g] = __builtin_amdgcn_mfma_f32_16x16x32_bf16(af, bf, acc[g], 0, 0, 0);
            }
        }
    }

    // epilogue: bias + relu; D mapping: row = quad*4 + q, col = g*16 + l15
#pragma unroll
    for (int g = 0; g < 8; ++g) {
        const int col = g * 16 + l15;
        const float bb = bias[col];
#pragma unroll
        for (int q = 0; q < 4; ++q) {
            const int row = n0 + wave * 16 + quad * 4 + q;
            if (row < NN)
                out[(size_t)row * D + col] = fmaxf(acc[g][q] + bb, 0.f);
        }
    }
}

extern "C" void kernel_launch(void* const* d_in, const int* in_sizes, int n_in,
                              void* d_out, int out_size, void* d_ws, size_t ws_size,
                              hipStream_t stream) {
    const float* x = (const float*)d_in[0];
    const int* ei = (const int*)d_in[1];
    const int* et = (const int*)d_in[2];
    const float* w1 = (const float*)d_in[3];
    const float* root1 = (const float*)d_in[4];
    const float* b1 = (const float*)d_in[5];
    const float* w2 = (const float*)d_in[6];
    const float* root2 = (const float*)d_in[7];
    const float* b2 = (const float*)d_in[8];
    float* out = (float*)d_out;

    char* ws = (char*)d_ws;
    float* cnt = (float*)ws;                                    // N*R fp32 (1.6 MB)
    float* agg = (float*)(ws + (size_t)1600000);                // N*R*D fp32 (204.8 MB)
    float* h = (float*)(ws + (size_t)1600000 + 204800000);      // N*D fp32 (25.6 MB)
    u16* Bf1 = (u16*)(ws + (size_t)1600000 + 204800000 + 25600000);       // 294912 B
    u16* Bf2 = (u16*)(ws + (size_t)1600000 + 204800000 + 25600000 + 294912);

    const int* srcp = ei;
    const int* dstp = ei + EE;

    const size_t agg_bytes = (size_t)NN * R * D * sizeof(float);

    // counts + inverse (shared by both layers), weight packing
    hipMemsetAsync(cnt, 0, (size_t)NN * R * sizeof(float), stream);
    cnt_kernel<<<(EE + 255) / 256, 256, 0, stream>>>(dstp, et, cnt, EE);
    inv_kernel<<<(NN * R + 255) / 256, 256, 0, stream>>>(cnt, NN * R);
    bprep_kernel<<<(NCHUNK * 8 * 64 + 255) / 256, 256, 0, stream>>>(w1, root1, Bf1);
    bprep_kernel<<<(NCHUNK * 8 * 64 + 255) / 256, 256, 0, stream>>>(w2, root2, Bf2);

    const int scatter_blocks = EE / 4;  // one wave per edge, 4 waves/block
    const int gemm_blocks = (NN + 63) / 64;

    // layer 1: x -> h
    hipMemsetAsync(agg, 0, agg_bytes, stream);
    scatter_kernel<<<scatter_blocks, 256, 0, stream>>>(x, srcp, dstp, et, agg, EE);
    gemm_mfma<<<gemm_blocks, 256, 0, stream>>>(x, agg, cnt, Bf1, b1, h);

    // layer 2: h -> out
    hipMemsetAsync(agg, 0, agg_bytes, stream);
    scatter_kernel<<<scatter_blocks, 256, 0, stream>>>(h, srcp, dstp, et, agg, EE);
    gemm_mfma<<<gemm_blocks, 256, 0, stream>>>(h, agg, cnt, Bf2, b2, out);
}